// Round 10
// baseline (95.956 us; speedup 1.0000x reference)
//
#include <hip/hip_runtime.h>

// STAttn v9 = R9 "resident" with the spill fixed: __launch_bounds__(512,1).
// R9 post-mortem: (512,2) capped VGPR at 124 < bar[128] -> ue_w register
// cache spilled to scratch; spill VMEM ops also corrupted the counted
// vmcnt waits. LDS (145KB) forces 1 block/CU regardless, so ",1" loses
// nothing and restores the 256-VGPR budget (expect VGPR_Count ~190).
//
// Structure (unchanged from R9):
//   Kernel A: 1024 blocks (1 bt) x 512 thr (8 waves = (nh,jh,kh)).
//   - ue_w quadrant -> 128 VGPRs/lane, loaded ONCE (L2-hot), oldest in FIFO.
//   - ALL of x (128KB) staged to LDS via 16 global_load_lds/wave issued
//     up-front; consumed with monotone counted waits vmcnt(14-2t);
//     one s_barrier per 64-col tile; zero re-issue.
//   - LDS swizzle: 8B unit u of row r stored at u^(r&30) (16B contiguity).
//   - bf16 hi/lo trunc-split, 3x mfma_f32_32x32x16_bf16 per 16-k step.
//   - pooling reads x from LDS (x touches HBM exactly once).
//   Kernel B (fc2): attr @ fc1_w^T, as R6.

typedef __attribute__((ext_vector_type(8)))  short bf16x8;
typedef __attribute__((ext_vector_type(16))) float f32x16;

#define AS3(p) ((__attribute__((address_space(3))) void*)(p))
#define AS1(p) ((const __attribute__((address_space(1))) void*)(p))
#define SCHEDB() __builtin_amdgcn_sched_barrier(0)

// fp32 -> bf16 hi (trunc) + lo (residual, trunc); alo*blo (~2^-16) dropped.
__device__ __forceinline__ void split8t(const float* __restrict__ v,
                                        bf16x8& h8, bf16x8& l8) {
#pragma unroll
    for (int i = 0; i < 8; ++i) {
        const unsigned u = __float_as_uint(v[i]);
        h8[i] = (short)(u >> 16);
        const float hf = __uint_as_float(u & 0xFFFF0000u);
        l8[i] = (short)(__float_as_uint(v[i] - hf) >> 16);
    }
}

template<int MODE>
__global__ __launch_bounds__(512, 1) void stattn_main(
    const float* __restrict__ inp,    // [1024][64][512]
    const float* __restrict__ ue_w,   // [64][512]
    const float* __restrict__ ue_b,   // [64]
    const float* __restrict__ be,     // [64]
    const float* __restrict__ w_w,    // [64]
    const float* __restrict__ fc1_w,  // [256][512] (MODE 1 only)
    const float* __restrict__ fc1_b,  // [256]      (MODE 1 only)
    float* __restrict__ dst)          // MODE 0: attr[1024][512]; MODE 1: out
{
    // x tiles: [t][row][64 cols]; 8B unit u of row r stored at u^(r&30).
    __shared__ __align__(16) float x_lds[8][64][64];  // 128 KB
    __shared__ __align__(16) float comb[4096];        // 16 KB scratch
    __shared__ float ep_s[2][64];
    __shared__ float a_s[64];

    const int tid = threadIdx.x;
    const int wv  = tid >> 6;
    const int l   = tid & 63;
    const int l31 = l & 31;
    const int hi5 = l >> 5;
    const int kh  = wv & 1;         // 32-col half within each 64-col tile
    const int jh  = (wv >> 1) & 1;  // hidden half
    const int nh  = wv >> 2;        // token half
    const float* __restrict__ xg = inp + (size_t)blockIdx.x * (64 * 512);

    // ---- ue_w quadrant -> registers (issued FIRST; oldest in vmcnt FIFO) ----
    float bar[128];  // [t*2+s][8] elems, cols t*64 + kh*32 + s*16 + hi5*8 + e
    {
        const float* __restrict__ bp =
            ue_w + (jh * 32 + l31) * 512 + kh * 32 + hi5 * 8;
#pragma unroll
        for (int t = 0; t < 8; ++t)
#pragma unroll
            for (int s = 0; s < 2; ++s) {
                *reinterpret_cast<float4*>(&bar[(t * 2 + s) * 8]) =
                    *reinterpret_cast<const float4*>(&bp[t * 64 + s * 16]);
                *reinterpret_cast<float4*>(&bar[(t * 2 + s) * 8 + 4]) =
                    *reinterpret_cast<const float4*>(&bp[t * 64 + s * 16 + 4]);
            }
    }
    SCHEDB();

    // ---- issue ALL 16 x-staging instrs (tile-ordered; pinned per tile) ----
    {
        const int r0 = wv * 8 + (l >> 4);
        const int r1 = r0 + 4;
        const float* __restrict__ gx0 =
            xg + r0 * 512 + 2 * (((l & 15) * 2) ^ (r0 & 30));
        const float* __restrict__ gx1 =
            xg + r1 * 512 + 2 * (((l & 15) * 2) ^ (r1 & 30));
#pragma unroll
        for (int t = 0; t < 8; ++t) {
            __builtin_amdgcn_global_load_lds(AS1(gx0 + t * 64),
                AS3(&x_lds[t][wv * 8][0]), 16, 0, 0);
            __builtin_amdgcn_global_load_lds(AS1(gx1 + t * 64),
                AS3(&x_lds[t][wv * 8 + 4][0]), 16, 0, 0);
            SCHEDB();  // pin FIFO order tile-by-tile
        }
    }

    f32x16 acc = {};
    const int arow = nh * 32 + l31;
    const int am   = arow & 30;

#define KSTEP(T, S) do {                                                      \
    float av[8];                                                              \
    const int qb_ = kh * 16 + (S) * 8 + hi5 * 4;                              \
    *reinterpret_cast<float2*>(&av[0]) = *reinterpret_cast<const float2*>(    \
        &x_lds[T][arow][(((qb_ + 0) ^ am)) * 2]);                             \
    *reinterpret_cast<float2*>(&av[2]) = *reinterpret_cast<const float2*>(    \
        &x_lds[T][arow][(((qb_ + 1) ^ am)) * 2]);                             \
    *reinterpret_cast<float2*>(&av[4]) = *reinterpret_cast<const float2*>(    \
        &x_lds[T][arow][(((qb_ + 2) ^ am)) * 2]);                             \
    *reinterpret_cast<float2*>(&av[6]) = *reinterpret_cast<const float2*>(    \
        &x_lds[T][arow][(((qb_ + 3) ^ am)) * 2]);                             \
    bf16x8 ah, al, bh, bl;                                                    \
    split8t(av, ah, al);                                                      \
    split8t(&bar[((T) * 2 + (S)) * 8], bh, bl);                               \
    acc = __builtin_amdgcn_mfma_f32_32x32x16_bf16(ah, bh, acc, 0, 0, 0);      \
    acc = __builtin_amdgcn_mfma_f32_32x32x16_bf16(al, bh, acc, 0, 0, 0);      \
    acc = __builtin_amdgcn_mfma_f32_32x32x16_bf16(ah, bl, acc, 0, 0, 0);      \
} while (0)

#define TILE(T, VM) do {                                                      \
    asm volatile("s_waitcnt vmcnt(" #VM ")" ::: "memory"); SCHEDB();          \
    __builtin_amdgcn_s_barrier(); SCHEDB();                                   \
    KSTEP(T, 0); KSTEP(T, 1);                                                 \
} while (0)

    // monotone counted waits: tile t needs its 2 staging instrs done ->
    // allowed outstanding = 14-2t (the 32 bar loads are older => also done).
    TILE(0, 14); TILE(1, 12); TILE(2, 10); TILE(3, 8);
    TILE(4, 6);  TILE(5, 4);  TILE(6, 2);  TILE(7, 0);
#undef TILE
#undef KSTEP

    // ---- kh-combine via comb scratch ----
    __syncthreads();
    {
        const int toff = (nh * 2 + jh) * 1024 + l;
        if (kh == 1) {
#pragma unroll
            for (int r = 0; r < 16; ++r) comb[toff + r * 64] = acc[r];
        }
        __syncthreads();
        if (kh == 0) {
#pragma unroll
            for (int r = 0; r < 16; ++r) acc[r] += comb[toff + r * 64];
            // phase 2: bias + lrelu + dot w_w (w_b dropped: softmax shift-inv)
            // C/D layout: col j = l&31, row n = (r&3) + 8*(r>>2) + 4*(l>>5)
            const int j = jh * 32 + l31;
            const float bias = ue_b[j] + be[j];
            const float ww   = w_w[j];
#pragma unroll
            for (int r = 0; r < 16; ++r) {
                float hv = acc[r] + bias;
                hv = hv > 0.f ? hv : 0.2f * hv;
                float p = hv * ww;
                p += __shfl_xor(p, 1);
                p += __shfl_xor(p, 2);
                p += __shfl_xor(p, 4);
                p += __shfl_xor(p, 8);
                p += __shfl_xor(p, 16);
                if (l31 == 0) {
                    const int nr = (r & 3) + 8 * (r >> 2) + 4 * hi5;
                    ep_s[jh][nh * 32 + nr] = p;
                }
            }
        }
    }
    __syncthreads();

    // ---- softmax over 64 tokens ----
    {
        const float v = ep_s[0][l] + ep_s[1][l];
        float mx = v;
#pragma unroll
        for (int off = 32; off >= 1; off >>= 1) mx = fmaxf(mx, __shfl_xor(mx, off));
        const float ex = expf(v - mx);
        float sm = ex;
#pragma unroll
        for (int off = 32; off >= 1; off >>= 1) sm += __shfl_xor(sm, off);
        if (wv == 0) a_s[l] = ex / sm;
    }
    __syncthreads();

    // ---- pooling from LDS: wave wv sums n in [wv*8, wv*8+8) ----
    {
        float pa0 = 0.f, pa1 = 0.f, pa2 = 0.f, pa3 = 0.f;
        float pb0 = 0.f, pb1 = 0.f, pb2 = 0.f, pb3 = 0.f;
        const int t0 = l >> 4;
        const int u0 = (2 * l) & 31;
#pragma unroll
        for (int n8 = 0; n8 < 8; ++n8) {
            const int n  = wv * 8 + n8;
            const float an = a_s[n];
            const int ph = (u0 ^ (n & 30)) * 2;
            const float4 v0 = *reinterpret_cast<const float4*>(&x_lds[t0][n][ph]);
            const float4 v1 = *reinterpret_cast<const float4*>(&x_lds[t0 + 4][n][ph]);
            pa0 = fmaf(an, v0.x, pa0); pa1 = fmaf(an, v0.y, pa1);
            pa2 = fmaf(an, v0.z, pa2); pa3 = fmaf(an, v0.w, pa3);
            pb0 = fmaf(an, v1.x, pb0); pb1 = fmaf(an, v1.y, pb1);
            pb2 = fmaf(an, v1.z, pb2); pb3 = fmaf(an, v1.w, pb3);
        }
        float4 o0; o0.x = pa0; o0.y = pa1; o0.z = pa2; o0.w = pa3;
        float4 o1; o1.x = pb0; o1.y = pb1; o1.z = pb2; o1.w = pb3;
        *reinterpret_cast<float4*>(&comb[wv * 512 + 4 * l])       = o0;
        *reinterpret_cast<float4*>(&comb[wv * 512 + 4 * l + 256]) = o1;
    }
    __syncthreads();

    // ---- reduce 8 wave-partials; write attr ----
    {
        const int d = tid;
        float s = 0.f;
#pragma unroll
        for (int w = 0; w < 8; ++w) s += comb[w * 512 + d];
        if (MODE == 0) {
            dst[(size_t)blockIdx.x * 512 + d] = s;
        } else {
            reinterpret_cast<float*>(x_lds)[d] = s;  // x dead; reuse as attr
        }
    }

    if (MODE == 1) {
        __syncthreads();
        const int o  = tid >> 1;
        const int ks = tid & 1;
        const float* __restrict__ wr = fc1_w + o * 512 + ks * 256;
        const float* __restrict__ ap = reinterpret_cast<float*>(x_lds) + ks * 256;
        float s0 = 0.f, s1 = 0.f, s2 = 0.f, s3 = 0.f;
#pragma unroll 8
        for (int i = 0; i < 64; ++i) {
            const float4 w4 = *reinterpret_cast<const float4*>(&wr[i * 4]);
            const float4 a4 = *reinterpret_cast<const float4*>(&ap[i * 4]);
            s0 = fmaf(a4.x, w4.x, s0);
            s1 = fmaf(a4.y, w4.y, s1);
            s2 = fmaf(a4.z, w4.z, s2);
            s3 = fmaf(a4.w, w4.w, s3);
        }
        float p = (s0 + s1) + (s2 + s3);
        p += __shfl_xor(p, 1);
        if (ks == 0) {
            const int bt  = blockIdx.x;
            const int row = (bt & 31) * 32 + (bt >> 5);
            dst[row * 256 + o] = p + fc1_b[o];
        }
    }
}

// fc GEMM: out[(bt&31)*32+(bt>>5)][o] = attr[bt] . fc1_w[o] + fc1_b[o]
__global__ __launch_bounds__(256, 2) void stattn_fc2(
    const float* __restrict__ attr,   // [1024][512] (d_ws)
    const float* __restrict__ fc1_w,  // [256][512]
    const float* __restrict__ fc1_b,  // [256]
    float* __restrict__ out)          // [1024][256]
{
    __shared__ __align__(16) float at[32][516];
    const int tid = threadIdx.x;
    const int bm  = blockIdx.x;
    const int bn  = blockIdx.y;

    {
        const int row = tid >> 3;
        const int seg = tid & 7;
        const float* __restrict__ src = attr + (size_t)(bm * 32 + row) * 512 + seg * 64;
#pragma unroll
        for (int q = 0; q < 16; ++q)
            *reinterpret_cast<float4*>(&at[row][seg * 64 + q * 4]) =
                *reinterpret_cast<const float4*>(&src[q * 4]);
    }
    __syncthreads();

    const int tx = tid & 31;
    const int ty = tid >> 5;
    const int o  = bn * 32 + tx;
    const float* __restrict__ wr = fc1_w + (size_t)o * 512;
    float s0 = 0.f, s1 = 0.f, s2 = 0.f, s3 = 0.f;
#pragma unroll 4
    for (int kq = 0; kq < 128; ++kq) {
        const float4 w4 = *reinterpret_cast<const float4*>(&wr[kq * 4]);
        const float4 a0 = *reinterpret_cast<const float4*>(&at[ty * 4 + 0][kq * 4]);
        const float4 a1 = *reinterpret_cast<const float4*>(&at[ty * 4 + 1][kq * 4]);
        const float4 a2 = *reinterpret_cast<const float4*>(&at[ty * 4 + 2][kq * 4]);
        const float4 a3 = *reinterpret_cast<const float4*>(&at[ty * 4 + 3][kq * 4]);
        s0 += a0.x * w4.x + a0.y * w4.y + a0.z * w4.z + a0.w * w4.w;
        s1 += a1.x * w4.x + a1.y * w4.y + a1.z * w4.z + a1.w * w4.w;
        s2 += a2.x * w4.x + a2.y * w4.y + a2.z * w4.z + a2.w * w4.w;
        s3 += a3.x * w4.x + a3.y * w4.y + a3.z * w4.z + a3.w * w4.w;
    }
    const float fb = fc1_b[o];
    float sv[4] = {s0, s1, s2, s3};
#pragma unroll
    for (int j = 0; j < 4; ++j) {
        const int bt  = bm * 32 + ty * 4 + j;
        const int row = (bt & 31) * 32 + (bt >> 5);
        out[row * 256 + o] = sv[j] + fb;
    }
}

extern "C" void kernel_launch(void* const* d_in, const int* in_sizes, int n_in,
                              void* d_out, int out_size, void* d_ws, size_t ws_size,
                              hipStream_t stream) {
    const float* inp   = (const float*)d_in[0];
    const float* ue_w  = (const float*)d_in[1];
    const float* ue_b  = (const float*)d_in[2];
    const float* be    = (const float*)d_in[3];
    const float* w_w   = (const float*)d_in[4];
    // d_in[5] = w_b: unused (softmax invariant to constant shift)
    const float* fc1_w = (const float*)d_in[6];
    const float* fc1_b = (const float*)d_in[7];
    float* out = (float*)d_out;

    const bool split = ws_size >= (size_t)1024 * 512 * 4;  // 2MB (confirmed R6)
    if (split) {
        float* attr = (float*)d_ws;
        stattn_main<0><<<1024, 512, 0, stream>>>(inp, ue_w, ue_b, be, w_w,
                                                 fc1_w, fc1_b, attr);
        stattn_fc2<<<dim3(32, 8), 256, 0, stream>>>(attr, fc1_w, fc1_b, out);
    } else {
        stattn_main<1><<<1024, 512, 0, stream>>>(inp, ue_w, ue_b, be, w_w,
                                                 fc1_w, fc1_b, out);
    }
}

// Round 11
// 90.576 us; speedup vs baseline: 1.0594x; 1.0594x over previous
//
#include <hip/hip_runtime.h>

// STAttn v10 "wave-streaming": B,T,N,D=32,32,64,512; H=64; OUT=256.
// Kernel 1 (stattn_ea): 512 blocks x 256 thr (4 waves). wave = (g, nh):
//   g = bt within block (2 bt/block), nh = token half (32 tokens).
//   - GEMM h(32x64,K=512) per wave: operands DIRECT global->fragment
//     (no LDS staging, ZERO barriers in k-loop). acc in 2x f32x16.
//   - bf16 hi/lo trunc-split, 3 MFMA per 16-k step per j-half.
//   - e = lrelu(h+bias)@w_w reduced in-wave; 2 block barriers total
//     (e-exchange, a-publish); softmax in-wave; pooling = second streamed
//     pass over x (L2/L3-hot, coalesced float4, no barriers).
//   Waves de-phase naturally -> VMEM/VALU/MFMA interleave across waves.
// Kernel 2 (stattn_fc2): attr @ fc1_w^T + b (proven R6).
// MODE 1 fallback (small ws): fc fused in-block.

typedef __attribute__((ext_vector_type(8)))  short bf16x8;
typedef __attribute__((ext_vector_type(16))) float f32x16;

// one float -> bf16 hi (trunc) + lo (residual, trunc); alo*blo (~2^-16) dropped
#define SPL(f, i) do {                                                        \
    const unsigned u_ = __float_as_uint(f);                                   \
    h8[i] = (short)(u_ >> 16);                                                \
    const float hf_ = __uint_as_float(u_ & 0xFFFF0000u);                      \
    l8[i] = (short)(__float_as_uint((f) - hf_) >> 16);                        \
} while (0)

__device__ __forceinline__ void split8v(float4 va, float4 vb,
                                        bf16x8& h8, bf16x8& l8) {
    SPL(va.x, 0); SPL(va.y, 1); SPL(va.z, 2); SPL(va.w, 3);
    SPL(vb.x, 4); SPL(vb.y, 5); SPL(vb.z, 6); SPL(vb.w, 7);
}

template<int MODE>
__global__ __launch_bounds__(256, 2) void stattn_ea(
    const float* __restrict__ inp,    // [1024][64][512]
    const float* __restrict__ ue_w,   // [64][512]
    const float* __restrict__ ue_b,   // [64]
    const float* __restrict__ be,     // [64]
    const float* __restrict__ w_w,    // [64]
    const float* __restrict__ fc1_w,  // [256][512] (MODE 1 only)
    const float* __restrict__ fc1_b,  // [256]      (MODE 1 only)
    float* __restrict__ dst)          // MODE 0: attr[1024][512]; MODE 1: out
{
    __shared__ float e_s[2][64];
    __shared__ float a_s[2][64];
    __shared__ __align__(16) float attr_s[2][512];  // MODE 1 only

    const int tid = threadIdx.x;
    const int wv  = tid >> 6;
    const int l   = tid & 63;
    const int l31 = l & 31;
    const int hi5 = l >> 5;
    const int g   = wv >> 1;        // bt within block
    const int nh  = wv & 1;         // token half
    const long bt = (long)blockIdx.x * 2 + g;
    const float* __restrict__ xg = inp + bt * (64 * 512);

    // ---- phase 1: h-GEMM, direct global->fragment, zero barriers ----
    const float* __restrict__ arow  = xg   + (nh * 32 + l31) * 512 + hi5 * 8;
    const float* __restrict__ brow0 = ue_w + l31 * 512 + hi5 * 8;          // j 0..31
    const float* __restrict__ brow1 = brow0 + 32 * 512;                    // j 32..63

    f32x16 acc0 = {}, acc1 = {};
#pragma unroll 4
    for (int ks = 0; ks < 32; ++ks) {
        const int k = ks * 16;
        const float4 a0  = *reinterpret_cast<const float4*>(&arow[k]);
        const float4 a1  = *reinterpret_cast<const float4*>(&arow[k + 4]);
        const float4 b00 = *reinterpret_cast<const float4*>(&brow0[k]);
        const float4 b01 = *reinterpret_cast<const float4*>(&brow0[k + 4]);
        const float4 b10 = *reinterpret_cast<const float4*>(&brow1[k]);
        const float4 b11 = *reinterpret_cast<const float4*>(&brow1[k + 4]);
        bf16x8 ah, al, bh0, bl0, bh1, bl1;
        { bf16x8 &h8 = ah,  &l8 = al;  split8v(a0,  a1,  h8, l8); }
        { bf16x8 &h8 = bh0, &l8 = bl0; split8v(b00, b01, h8, l8); }
        { bf16x8 &h8 = bh1, &l8 = bl1; split8v(b10, b11, h8, l8); }
        acc0 = __builtin_amdgcn_mfma_f32_32x32x16_bf16(ah, bh0, acc0, 0, 0, 0);
        acc0 = __builtin_amdgcn_mfma_f32_32x32x16_bf16(al, bh0, acc0, 0, 0, 0);
        acc0 = __builtin_amdgcn_mfma_f32_32x32x16_bf16(ah, bl0, acc0, 0, 0, 0);
        acc1 = __builtin_amdgcn_mfma_f32_32x32x16_bf16(ah, bh1, acc1, 0, 0, 0);
        acc1 = __builtin_amdgcn_mfma_f32_32x32x16_bf16(al, bh1, acc1, 0, 0, 0);
        acc1 = __builtin_amdgcn_mfma_f32_32x32x16_bf16(ah, bl1, acc1, 0, 0, 0);
    }

    // ---- phase 2: e = lrelu(h+bias)@w_w (w_b dropped: softmax shift-inv) ----
    // C/D layout (m74/m101): col j = l&31, row n = (r&3) + 8*(r>>2) + 4*(l>>5)
    {
        const int j0 = l31, j1 = l31 + 32;
        const float bias0 = ue_b[j0] + be[j0];
        const float bias1 = ue_b[j1] + be[j1];
        const float ww0 = w_w[j0], ww1 = w_w[j1];
#pragma unroll
        for (int r = 0; r < 16; ++r) {
            float h0 = acc0[r] + bias0; h0 = h0 > 0.f ? h0 : 0.2f * h0;
            float h1 = acc1[r] + bias1; h1 = h1 > 0.f ? h1 : 0.2f * h1;
            float p = h0 * ww0 + h1 * ww1;
            p += __shfl_xor(p, 1);
            p += __shfl_xor(p, 2);
            p += __shfl_xor(p, 4);
            p += __shfl_xor(p, 8);
            p += __shfl_xor(p, 16);
            if (l31 == 0)
                e_s[g][nh * 32 + (r & 3) + 8 * (r >> 2) + 4 * hi5] = p;
        }
    }
    __syncthreads();

    // ---- softmax over 64 tokens (both waves of g compute; same value) ----
    {
        const float v = e_s[g][l];
        float mx = v;
#pragma unroll
        for (int off = 32; off >= 1; off >>= 1) mx = fmaxf(mx, __shfl_xor(mx, off));
        const float ex = expf(v - mx);
        float sm = ex;
#pragma unroll
        for (int off = 32; off >= 1; off >>= 1) sm += __shfl_xor(sm, off);
        a_s[g][l] = ex / sm;   // both waves write identical value: benign
    }
    __syncthreads();

    // ---- phase 3: pooling, second streamed pass (L2/L3-hot), no barriers ----
    {
        const float* __restrict__ xp = xg + nh * 256 + 4 * l;
        float sx = 0.f, sy = 0.f, sz = 0.f, sw = 0.f;
#pragma unroll 8
        for (int n = 0; n < 64; ++n) {
            const float an  = a_s[g][n];
            const float4 xv = *reinterpret_cast<const float4*>(&xp[n * 512]);
            sx = fmaf(an, xv.x, sx);
            sy = fmaf(an, xv.y, sy);
            sz = fmaf(an, xv.z, sz);
            sw = fmaf(an, xv.w, sw);
        }
        float4 o; o.x = sx; o.y = sy; o.z = sz; o.w = sw;
        if (MODE == 0) {
            *reinterpret_cast<float4*>(&dst[bt * 512 + nh * 256 + 4 * l]) = o;
        } else {
            *reinterpret_cast<float4*>(&attr_s[g][nh * 256 + 4 * l]) = o;
        }
    }

    if (MODE == 1) {
        __syncthreads();
        const int o = tid;
#pragma unroll
        for (int gg = 0; gg < 2; ++gg) {
            const float* __restrict__ wr = fc1_w + o * 512;
            const float* __restrict__ ap = attr_s[gg];
            float s0 = 0.f, s1 = 0.f, s2 = 0.f, s3 = 0.f;
#pragma unroll 8
            for (int i = 0; i < 128; ++i) {
                const float4 w4 = *reinterpret_cast<const float4*>(&wr[i * 4]);
                const float4 a4 = *reinterpret_cast<const float4*>(&ap[i * 4]);
                s0 = fmaf(a4.x, w4.x, s0);
                s1 = fmaf(a4.y, w4.y, s1);
                s2 = fmaf(a4.z, w4.z, s2);
                s3 = fmaf(a4.w, w4.w, s3);
            }
            const long btg = (long)blockIdx.x * 2 + gg;
            const int row  = (int)(btg & 31) * 32 + (int)(btg >> 5);
            dst[row * 256 + o] = (s0 + s1) + (s2 + s3) + fc1_b[o];
        }
    }
}

// fc GEMM: out[(bt&31)*32+(bt>>5)][o] = attr[bt] . fc1_w[o] + fc1_b[o]
__global__ __launch_bounds__(256, 2) void stattn_fc2(
    const float* __restrict__ attr,   // [1024][512] (d_ws)
    const float* __restrict__ fc1_w,  // [256][512]
    const float* __restrict__ fc1_b,  // [256]
    float* __restrict__ out)          // [1024][256]
{
    __shared__ __align__(16) float at[32][516];
    const int tid = threadIdx.x;
    const int bm  = blockIdx.x;
    const int bn  = blockIdx.y;

    {
        const int row = tid >> 3;
        const int seg = tid & 7;
        const float* __restrict__ src = attr + (size_t)(bm * 32 + row) * 512 + seg * 64;
#pragma unroll
        for (int q = 0; q < 16; ++q)
            *reinterpret_cast<float4*>(&at[row][seg * 64 + q * 4]) =
                *reinterpret_cast<const float4*>(&src[q * 4]);
    }
    __syncthreads();

    const int tx = tid & 31;
    const int ty = tid >> 5;
    const int o  = bn * 32 + tx;
    const float* __restrict__ wr = fc1_w + (size_t)o * 512;
    float s0 = 0.f, s1 = 0.f, s2 = 0.f, s3 = 0.f;
#pragma unroll 4
    for (int kq = 0; kq < 128; ++kq) {
        const float4 w4 = *reinterpret_cast<const float4*>(&wr[kq * 4]);
        const float4 a0 = *reinterpret_cast<const float4*>(&at[ty * 4 + 0][kq * 4]);
        const float4 a1 = *reinterpret_cast<const float4*>(&at[ty * 4 + 1][kq * 4]);
        const float4 a2 = *reinterpret_cast<const float4*>(&at[ty * 4 + 2][kq * 4]);
        const float4 a3 = *reinterpret_cast<const float4*>(&at[ty * 4 + 3][kq * 4]);
        s0 += a0.x * w4.x + a0.y * w4.y + a0.z * w4.z + a0.w * w4.w;
        s1 += a1.x * w4.x + a1.y * w4.y + a1.z * w4.z + a1.w * w4.w;
        s2 += a2.x * w4.x + a2.y * w4.y + a2.z * w4.z + a2.w * w4.w;
        s3 += a3.x * w4.x + a3.y * w4.y + a3.z * w4.z + a3.w * w4.w;
    }
    const float fb = fc1_b[o];
    float sv0 = s0 + fb, sv1 = s1 + fb, sv2 = s2 + fb, sv3 = s3 + fb;
    {
        int btv = bm * 32 + ty * 4;
        out[((btv & 31) * 32 + (btv >> 5)) * 256 + o] = sv0; ++btv;
        out[((btv & 31) * 32 + (btv >> 5)) * 256 + o] = sv1; ++btv;
        out[((btv & 31) * 32 + (btv >> 5)) * 256 + o] = sv2; ++btv;
        out[((btv & 31) * 32 + (btv >> 5)) * 256 + o] = sv3;
    }
}

extern "C" void kernel_launch(void* const* d_in, const int* in_sizes, int n_in,
                              void* d_out, int out_size, void* d_ws, size_t ws_size,
                              hipStream_t stream) {
    const float* inp   = (const float*)d_in[0];
    const float* ue_w  = (const float*)d_in[1];
    const float* ue_b  = (const float*)d_in[2];
    const float* be    = (const float*)d_in[3];
    const float* w_w   = (const float*)d_in[4];
    // d_in[5] = w_b: unused (softmax invariant to constant shift)
    const float* fc1_w = (const float*)d_in[6];
    const float* fc1_b = (const float*)d_in[7];
    float* out = (float*)d_out;

    const bool split = ws_size >= (size_t)1024 * 512 * 4;  // 2MB (confirmed R6)
    if (split) {
        float* attr = (float*)d_ws;
        stattn_ea<0><<<512, 256, 0, stream>>>(inp, ue_w, ue_b, be, w_w,
                                              fc1_w, fc1_b, attr);
        stattn_fc2<<<dim3(32, 8), 256, 0, stream>>>(attr, fc1_w, fc1_b, out);
    } else {
        stattn_ea<1><<<512, 256, 0, stream>>>(inp, ue_w, ue_b, be, w_w,
                                              fc1_w, fc1_b, out);
    }
}